// Round 1
// baseline (330.486 us; speedup 1.0000x reference)
//
#include <hip/hip_runtime.h>
#include <hip/hip_bf16.h>

#define GROUPS 16
#define BSZ    8192
#define CHN    256

using f32x4  = __attribute__((ext_vector_type(4))) float;
using bf16x8 = __attribute__((ext_vector_type(8))) __bf16;

static __device__ __forceinline__ unsigned short f32_bf16(float f) {
    unsigned int u = __builtin_bit_cast(unsigned int, f);
    u = (u + 0x7FFFu + ((u >> 16) & 1u)) >> 16;   // RNE (NaN not a concern here)
    return (unsigned short)u;
}
static __device__ __forceinline__ unsigned int pack_bf16x2(float lo, float hi) {
    return (unsigned int)f32_bf16(lo) | ((unsigned int)f32_bf16(hi) << 16);
}

// ---------------------------------------------------------------------------
// Kernel B: compose M = H_0 H_1 ... H_255 per group, row-parallel.
// Row r of M: m = e_r; for i: m -= (2/(w_i.w_i)) (m.w_i) w_i,  w_i = weight[g][:,i].
// Output: Mt[g][c][n] = M[n][c]  (bf16), n = k-dim for the GEMM.
// Block: 256 thr = 16 rows x 16 lanes.  Grid: 16 groups x 16 row-blocks.
// ---------------------------------------------------------------------------
__global__ __launch_bounds__(256) void compose_m(const float* __restrict__ weight,
                                                 unsigned short* __restrict__ Mt) {
    __shared__ float wbuf[16 * 260];   // 16 staged columns, stride 260 (pad)
    __shared__ float coefbuf[16];

    const int t    = threadIdx.x;
    const int g    = blockIdx.x >> 4;
    const int r0   = (blockIdx.x & 15) * 16;
    const int lane = t & 15;           // lane within row-group
    const int rg   = (t >> 4) & 3;     // row within wave
    const int wave = t >> 6;
    const int r    = r0 + wave * 4 + rg;   // this task's M row (0..255)

    // m held in registers: c = 4*lane + 64*j + e  (j=0..3, e=0..3)
    float4 m4[4];
#pragma unroll
    for (int j = 0; j < 4; ++j) {
        const int cb = 4 * lane + 64 * j;
        m4[j].x = (cb + 0 == r) ? 1.0f : 0.0f;
        m4[j].y = (cb + 1 == r) ? 1.0f : 0.0f;
        m4[j].z = (cb + 2 == r) ? 1.0f : 0.0f;
        m4[j].w = (cb + 3 == r) ? 1.0f : 0.0f;
    }

    const float* wg = weight + (size_t)g * CHN * CHN;
    const int e16 = t & 15;    // which column (i-offset) this thread stages
    const int nb  = t >> 4;    // n base (stride 16)

    for (int iw = 0; iw < 16; ++iw) {
        const int i0 = iw * 16;
        // issue global loads for this window before the barrier (no LDS hazard)
        float ld[16];
#pragma unroll
        for (int k = 0; k < 16; ++k)
            ld[k] = wg[(nb + 16 * k) * CHN + i0 + e16];
        __syncthreads();   // previous window fully consumed
#pragma unroll
        for (int k = 0; k < 16; ++k)
            wbuf[e16 * 260 + nb + 16 * k] = ld[k];
        __syncthreads();
        // coefs: thread group e (=t>>4) computes 2/(w_e . w_e)
        {
            const int e = t >> 4;
            float s = 0.0f;
#pragma unroll
            for (int k = 0; k < 16; ++k) {
                const float w = wbuf[e * 260 + lane + 16 * k];
                s += w * w;
            }
            s += __shfl_xor(s, 1);
            s += __shfl_xor(s, 2);
            s += __shfl_xor(s, 4);
            s += __shfl_xor(s, 8);
            if (lane == 0) coefbuf[e] = 2.0f / s;
        }
        __syncthreads();
        // 16 sequential reflection steps
#pragma unroll
        for (int e = 0; e < 16; ++e) {
            float4 w4[4];
#pragma unroll
            for (int j = 0; j < 4; ++j)
                w4[j] = *(const float4*)&wbuf[e * 260 + 4 * lane + 64 * j];
            float p = 0.0f;
#pragma unroll
            for (int j = 0; j < 4; ++j)
                p += m4[j].x * w4[j].x + m4[j].y * w4[j].y +
                     m4[j].z * w4[j].z + m4[j].w * w4[j].w;
            p += __shfl_xor(p, 1);
            p += __shfl_xor(p, 2);
            p += __shfl_xor(p, 4);
            p += __shfl_xor(p, 8);
            const float s = coefbuf[e] * p;
#pragma unroll
            for (int j = 0; j < 4; ++j) {
                m4[j].x -= s * w4[j].x;
                m4[j].y -= s * w4[j].y;
                m4[j].z -= s * w4[j].z;
                m4[j].w -= s * w4[j].w;
            }
        }
    }

    // write Mt[g][c][r] (bf16) — scattered u16 stores, tiny total (2 MB)
    unsigned short* mg = Mt + (size_t)g * CHN * CHN;
#pragma unroll
    for (int j = 0; j < 4; ++j) {
        const int cb = 4 * lane + 64 * j;
        mg[(size_t)(cb + 0) * CHN + r] = f32_bf16(m4[j].x);
        mg[(size_t)(cb + 1) * CHN + r] = f32_bf16(m4[j].y);
        mg[(size_t)(cb + 2) * CHN + r] = f32_bf16(m4[j].z);
        mg[(size_t)(cb + 3) * CHN + r] = f32_bf16(m4[j].w);
    }
}

// ---------------------------------------------------------------------------
// Kernel C: out[g] = x[g] (8192x256 f32->bf16) @ M[g] (256x256 bf16), f32 acc.
// Block: 512 thr = 8 waves as 2x4; block tile 128 rows x 256 cols;
// wave tile 64x64 (4x4 MFMA 16x16 tiles). K chunked at 64, single LDS buffer.
// LDS rows use dword-stride 37 (odd) -> frag reads via 4x ds_read_b32, ~2-way
// bank aliasing max (free).
// ---------------------------------------------------------------------------
__global__ __launch_bounds__(512, 4) void gemm_xm(const float* __restrict__ x,
                                                  const unsigned short* __restrict__ Mt,
                                                  float* __restrict__ out) {
    __shared__ unsigned int xa [128 * 37];  // x tile, bf16x2 per dword
    __shared__ unsigned int mts[256 * 37];  // Mt tile (c-major, k contiguous)

    const int t    = threadIdx.x;
    const int g    = blockIdx.x >> 6;
    const int rb   = blockIdx.x & 63;
    const int r0   = rb * 128;
    const int l    = t & 63;
    const int wave = t >> 6;     // 0..7
    const int wr   = wave >> 2;  // 0..1  (row half)
    const int wc   = wave & 3;   // 0..3  (col quarter)
    const int lm   = l & 15;
    const int q    = l >> 4;     // 0..3

    const float*          xg = x  + ((size_t)g * BSZ + r0) * CHN;
    const unsigned short* mg = Mt +  (size_t)g * CHN * CHN;

    f32x4 acc[4][4];
#pragma unroll
    for (int mi = 0; mi < 4; ++mi)
#pragma unroll
        for (int ni = 0; ni < 4; ++ni)
            acc[mi][ni] = (f32x4){0.f, 0.f, 0.f, 0.f};

    const int srr = t >> 4;   // x-stage row base (0..31, +32 per it)
    const int sk4 = t & 15;   // x-stage float4 index within 64-k chunk
    const int mc  = t >> 1;   // mt-stage column (0..255)
    const int mh  = t & 1;    // mt-stage k-half

    for (int kc = 0; kc < 4; ++kc) {
        const int k0 = kc * 64;
        __syncthreads();   // previous chunk's frag reads complete
        // stage x (f32 -> packed bf16x2): 128 rows x 64 k
#pragma unroll
        for (int it = 0; it < 4; ++it) {
            const int rr = srr + it * 32;
            const float4 v = *(const float4*)&xg[(size_t)rr * CHN + k0 + 4 * sk4];
            xa[rr * 37 + 2 * sk4 + 0] = pack_bf16x2(v.x, v.y);
            xa[rr * 37 + 2 * sk4 + 1] = pack_bf16x2(v.z, v.w);
        }
        // stage Mt: column mc, k in [k0+32*mh, +32): pure dword copy
        {
            const uint4* src = (const uint4*)(mg + (size_t)mc * CHN + k0 + 32 * mh);
#pragma unroll
            for (int s = 0; s < 4; ++s) {
                const uint4 v = src[s];
                const int base = mc * 37 + 16 * mh + 4 * s;
                mts[base + 0] = v.x;
                mts[base + 1] = v.y;
                mts[base + 2] = v.z;
                mts[base + 3] = v.w;
            }
        }
        __syncthreads();
        // compute: 2 k-steps of 32, 4x4 MFMA tiles
#pragma unroll
        for (int ks = 0; ks < 2; ++ks) {
            const int koff = 16 * ks + 4 * q;
            bf16x8 a[4], b[4];
#pragma unroll
            for (int mi = 0; mi < 4; ++mi) {
                const int rr = wr * 64 + mi * 16 + lm;
                uint4 u;
                u.x = xa[rr * 37 + koff + 0];
                u.y = xa[rr * 37 + koff + 1];
                u.z = xa[rr * 37 + koff + 2];
                u.w = xa[rr * 37 + koff + 3];
                a[mi] = __builtin_bit_cast(bf16x8, u);
            }
#pragma unroll
            for (int ni = 0; ni < 4; ++ni) {
                const int cc = wc * 64 + ni * 16 + lm;
                uint4 u;
                u.x = mts[cc * 37 + koff + 0];
                u.y = mts[cc * 37 + koff + 1];
                u.z = mts[cc * 37 + koff + 2];
                u.w = mts[cc * 37 + koff + 3];
                b[ni] = __builtin_bit_cast(bf16x8, u);
            }
#pragma unroll
            for (int mi = 0; mi < 4; ++mi)
#pragma unroll
                for (int ni = 0; ni < 4; ++ni)
                    acc[mi][ni] = __builtin_amdgcn_mfma_f32_16x16x32_bf16(
                        a[mi], b[ni], acc[mi][ni], 0, 0, 0);
        }
    }

    // epilogue: D layout col = lane&15, row = (lane>>4)*4 + reg
    float* og = out + ((size_t)g * BSZ + r0) * CHN;
#pragma unroll
    for (int mi = 0; mi < 4; ++mi) {
#pragma unroll
        for (int ni = 0; ni < 4; ++ni) {
            const int col = wc * 64 + ni * 16 + lm;
#pragma unroll
            for (int reg = 0; reg < 4; ++reg) {
                const int row = wr * 64 + mi * 16 + q * 4 + reg;
                og[(size_t)row * CHN + col] = acc[mi][ni][reg];
            }
        }
    }
}

extern "C" void kernel_launch(void* const* d_in, const int* in_sizes, int n_in,
                              void* d_out, int out_size, void* d_ws, size_t ws_size,
                              hipStream_t stream) {
    const float* x = (const float*)d_in[0];
    const float* w = (const float*)d_in[1];
    float* out = (float*)d_out;
    unsigned short* Mt = (unsigned short*)d_ws;   // 16*256*256 bf16 = 2 MB

    hipLaunchKernelGGL(compose_m, dim3(GROUPS * 16), dim3(256), 0, stream, w, Mt);
    hipLaunchKernelGGL(gemm_xm,   dim3(GROUPS * 64), dim3(512), 0, stream, x, Mt, out);
}